// Round 1
// baseline (14729.175 us; speedup 1.0000x reference)
//
#include <hip/hip_runtime.h>
#include <math.h>

#define BATCH 64
#define NREF  256
#define NPTS  2048
#define DIM   128
#define ITERS 100
#define INV_EPS 1000.0f

// Scaled (logit) domain throughout: u' = u/eps, v' = v/eps, C' = C/eps.

// ---------- branchless single-exp online LSE step ----------
__device__ __forceinline__ void lse_step(float t, float& m, float& s) {
    float nm = fmaxf(m, t);
    float e  = __expf(m + t - 2.0f * nm);      // exp(-|m-t|); 0 when m==-inf
    float s1 = fmaf(s, e, 1.0f);               // t is new max
    float s2 = s + e;                          // t <= m
    s = (t > m) ? s1 : s2;
    m = nm;
}
__device__ __forceinline__ void lse_combine(float& m, float& s, float mo, float so) {
    float nm = fmaxf(m, mo);
    s = s * __expf(m - nm) + so * __expf(mo - nm);
    m = nm;
}

// ---------- ref row norms ----------
__global__ __launch_bounds__(256) void r2_kernel(const float* __restrict__ ref,
                                                 float* __restrict__ r2) {
    int i = threadIdx.x;
    const float4* r4 = (const float4*)(ref + (size_t)i * DIM);
    float acc = 0.f;
#pragma unroll
    for (int k = 0; k < DIM / 4; ++k) {
        float4 a = r4[k];
        acc += a.x * a.x + a.y * a.y + a.z * a.z + a.w * a.w;
    }
    r2[i] = acc;
}

// ---------- C'[b][i][j] = sqrt(max(r2_i + x2_bj - 2*dot(ref_i, X_bj), 0)) * INV_EPS ----------
__global__ __launch_bounds__(256) void c_kernel(const float* __restrict__ X,
                                                const float* __restrict__ ref,
                                                const float* __restrict__ r2,
                                                float* __restrict__ C) {
    int b  = blockIdx.x >> 5;
    int it = (blockIdx.x >> 3) & 3;
    int jc = blockIdx.x & 7;
    int j  = jc * 256 + threadIdx.x;
    int i0 = it * 64;
    const float* xrow = X + ((size_t)b * NPTS + j) * DIM;

    float acc[64];
#pragma unroll
    for (int i = 0; i < 64; ++i) acc[i] = 0.f;
    float x2 = 0.f;

    for (int k0 = 0; k0 < DIM; k0 += 16) {
        float xv[16];
        const float4* xp = (const float4*)(xrow + k0);
#pragma unroll
        for (int q = 0; q < 4; ++q) {
            float4 t = xp[q];
            xv[q * 4 + 0] = t.x; xv[q * 4 + 1] = t.y;
            xv[q * 4 + 2] = t.z; xv[q * 4 + 3] = t.w;
        }
#pragma unroll
        for (int k = 0; k < 16; ++k) x2 = fmaf(xv[k], xv[k], x2);

        const float* rbase = ref + (size_t)i0 * DIM + k0;   // block-uniform -> s_load
#pragma unroll
        for (int i = 0; i < 64; ++i) {
            const float* rr = rbase + (size_t)i * DIM;
#pragma unroll
            for (int k = 0; k < 16; ++k) acc[i] = fmaf(rr[k], xv[k], acc[i]);
        }
    }

    float* cbase = C + ((size_t)b * NREF + i0) * NPTS + j;
#pragma unroll
    for (int i = 0; i < 64; ++i) {
        float sq = r2[i0 + i] + x2 - 2.f * acc[i];
        cbase[(size_t)i * NPTS] = sqrtf(fmaxf(sq, 0.f)) * INV_EPS;
    }
}

// ---------- u' update: one wave per row; two-pass, 1 exp/elem ----------
__global__ __launch_bounds__(256) void u_kernel(const float* __restrict__ C,
                                                const float* __restrict__ v,
                                                float* __restrict__ u,
                                                float log_wx,
                                                const unsigned int* __restrict__ stop) {
    if (*stop) return;                         // uniform scalar load; dead after convergence
    int row  = blockIdx.x * 4 + (threadIdx.x >> 6);   // b*256 + i
    int lane = threadIdx.x & 63;
    int b    = row >> 8;
    const float4* crow = (const float4*)(C + (size_t)row * NPTS);
    const float4* vrow = (const float4*)(v + (size_t)b * NPTS);

    float4 t[8];
    float m = -INFINITY;
#pragma unroll
    for (int c = 0; c < 8; ++c) {
        float4 cv = crow[c * 64 + lane];
        float4 vv = vrow[c * 64 + lane];
        float4 tt;
        tt.x = vv.x - cv.x; tt.y = vv.y - cv.y;
        tt.z = vv.z - cv.z; tt.w = vv.w - cv.w;
        t[c] = tt;
        m = fmaxf(m, fmaxf(fmaxf(tt.x, tt.y), fmaxf(tt.z, tt.w)));
    }
#pragma unroll
    for (int off = 1; off < 64; off <<= 1) m = fmaxf(m, __shfl_xor(m, off));

    float s0 = 0.f, s1 = 0.f, s2 = 0.f, s3 = 0.f;
#pragma unroll
    for (int c = 0; c < 8; ++c) {
        s0 += __expf(t[c].x - m);
        s1 += __expf(t[c].y - m);
        s2 += __expf(t[c].z - m);
        s3 += __expf(t[c].w - m);
    }
    float s = (s0 + s1) + (s2 + s3);
#pragma unroll
    for (int off = 1; off < 64; off <<= 1) s += __shfl_xor(s, off);

    if (lane == 0) u[row] = log_wx - (m + __logf(s));
}

// ---------- v' update + bitwise fixed-point / period-2 detection ----------
// Stopping rule (all bit-exact, deterministic map => zero numerical risk):
//   v^(t) == v^(t-1)                      -> all future states identical -> stop.
//   v^(t) == v^(t-2) and (ITERS-1-t) even -> period-2 cycle lands on final state -> stop.
//   (odd parity: the same check re-fires at t+1 with even parity -> handled.)
__global__ __launch_bounds__(256) void v_kernel(const float* __restrict__ C,
                                                const float* __restrict__ u,
                                                const float* __restrict__ vprev,
                                                float* __restrict__ vcur,
                                                float log_wy,
                                                unsigned int* __restrict__ flag_t,
                                                unsigned int* __restrict__ cnt_t,
                                                unsigned int* __restrict__ stop,
                                                unsigned int* __restrict__ final_p,
                                                int t) {
    if (*stop) return;
    __shared__ float sm[4][64];
    __shared__ float ss[4][64];
    int b  = blockIdx.x >> 5;
    int jc = blockIdx.x & 31;
    int jj = threadIdx.x & 63;
    int g  = threadIdx.x >> 6;          // wave index -> wave-uniform
    int j  = jc * 64 + jj;
    const float* cg = C + ((size_t)b * NREF + (size_t)g * 64) * NPTS + j;
    const float* ub = u + (size_t)b * NREF + g * 64;   // wave-uniform -> s_load

    float m0 = -INFINITY, s0 = 0.f, m1 = -INFINITY, s1 = 0.f;
#pragma unroll 8
    for (int i = 0; i < 64; i += 2) {
        float c0 = cg[(size_t)(i + 0) * NPTS];
        float c1 = cg[(size_t)(i + 1) * NPTS];
        lse_step(ub[i + 0] - c0, m0, s0);
        lse_step(ub[i + 1] - c1, m1, s1);
    }
    lse_combine(m0, s0, m1, s1);
    sm[g][jj] = m0; ss[g][jj] = s0;
    __syncthreads();
    if (g == 0) {
        float m = m0, s = s0;
#pragma unroll
        for (int q = 1; q < 4; ++q) lse_combine(m, s, sm[q][jj], ss[q][jj]);
        float vnew = log_wy - (m + __logf(s));
        size_t idx = (size_t)b * NPTS + j;
        float vo1 = vprev[idx];             // v^(t-1)
        float vo2 = vcur[idx];              // v^(t-2) (old content, before overwrite)
        vcur[idx] = vnew;
        unsigned long long b1 = __ballot(__float_as_uint(vnew) != __float_as_uint(vo1));
        unsigned long long b2 = __ballot(__float_as_uint(vnew) != __float_as_uint(vo2));
        if (threadIdx.x == 0) {
            unsigned int bits = (b1 ? 1u : 0u) | (b2 ? 2u : 0u);
            if (bits)
                __hip_atomic_fetch_or(flag_t, bits, __ATOMIC_RELEASE, __HIP_MEMORY_SCOPE_AGENT);
            unsigned int prior =
                __hip_atomic_fetch_add(cnt_t, 1u, __ATOMIC_ACQ_REL, __HIP_MEMORY_SCOPE_AGENT);
            if (prior == gridDim.x - 1u) {   // last block: all ORs for this iter visible
                unsigned int f = __hip_atomic_load(flag_t, __ATOMIC_RELAXED,
                                                   __HIP_MEMORY_SCOPE_AGENT);
                bool stop_now = ((f & 1u) == 0u) ||
                                (((f & 2u) == 0u) && (((ITERS - 1 - t) & 1) == 0));
                if (stop_now || t == ITERS - 1) {
                    *final_p = (unsigned int)(t & 1);
                    if (stop_now)
                        __hip_atomic_store(stop, 1u, __ATOMIC_RELEASE,
                                           __HIP_MEMORY_SCOPE_AGENT);
                }
            }
        }
    }
}

// ---------- epilogue v3: GEMM-style register tiling ----------
__global__ __launch_bounds__(256) void out_kernel(const float* __restrict__ C,
                                                  const float* __restrict__ X,
                                                  const float* __restrict__ ref,
                                                  const float* __restrict__ u,
                                                  const float* __restrict__ vb0,
                                                  const float* __restrict__ vb1,
                                                  const unsigned int* __restrict__ final_p,
                                                  float* __restrict__ out) {
    __shared__ float wt[32 * 32];       // [row_local][jj]  4 KB
    __shared__ float xt[32 * DIM];      // [jj][d]         16 KB
    const float* v = (*final_p) ? vb1 : vb0;   // uniform select of converged buffer
    int b  = blockIdx.x >> 3;
    int it = blockIdx.x & 7;
    int i0 = it * 32;
    int t  = threadIdx.x;
    int s  = t & 31;                    // d-slot (float4 at d = 4s)
    int g  = t >> 5;                    // rows i0 + g*4 .. +3

    const float* Cb = C + ((size_t)b * NREF + i0) * NPTS;
    const float* vb = v + (size_t)b * NPTS;
    const float* ub = u + (size_t)b * NREF + i0;

    float4 acc[4];
    float wsum[4];
#pragma unroll
    for (int r = 0; r < 4; ++r) { acc[r] = make_float4(0.f, 0.f, 0.f, 0.f); wsum[r] = 0.f; }

    for (int j0 = 0; j0 < NPTS; j0 += 32) {
        // stage w-tile: 32 rows x 32 jj (4 per thread, coalesced C reads)
#pragma unroll
        for (int k = 0; k < 4; ++k) {
            int widx = t + 256 * k;
            int r    = widx >> 5;
            int jj   = widx & 31;
            wt[widx] = __expf(ub[r] + vb[j0 + jj] - Cb[(size_t)r * NPTS + j0 + jj]);
        }
        // stage X-tile: 32 rows x 128 d = 1024 float4 (4 per thread)
        const float4* Xb4 = (const float4*)(X + ((size_t)b * NPTS + j0) * DIM);
#pragma unroll
        for (int k = 0; k < 4; ++k) {
            int idx = t + 256 * k;
            ((float4*)xt)[idx] = Xb4[idx];
        }
        __syncthreads();

        const float4* xt4 = (const float4*)xt;
#pragma unroll 2
        for (int jj = 0; jj < 32; jj += 4) {
            float4 xv0 = xt4[(jj + 0) * 32 + s];
            float4 xv1 = xt4[(jj + 1) * 32 + s];
            float4 xv2 = xt4[(jj + 2) * 32 + s];
            float4 xv3 = xt4[(jj + 3) * 32 + s];
#pragma unroll
            for (int r = 0; r < 4; ++r) {
                float4 w4 = *(const float4*)&wt[(g * 4 + r) * 32 + jj];
                acc[r].x = fmaf(w4.x, xv0.x, acc[r].x); acc[r].y = fmaf(w4.x, xv0.y, acc[r].y);
                acc[r].z = fmaf(w4.x, xv0.z, acc[r].z); acc[r].w = fmaf(w4.x, xv0.w, acc[r].w);
                acc[r].x = fmaf(w4.y, xv1.x, acc[r].x); acc[r].y = fmaf(w4.y, xv1.y, acc[r].y);
                acc[r].z = fmaf(w4.y, xv1.z, acc[r].z); acc[r].w = fmaf(w4.y, xv1.w, acc[r].w);
                acc[r].x = fmaf(w4.z, xv2.x, acc[r].x); acc[r].y = fmaf(w4.z, xv2.y, acc[r].y);
                acc[r].z = fmaf(w4.z, xv2.z, acc[r].z); acc[r].w = fmaf(w4.z, xv2.w, acc[r].w);
                acc[r].x = fmaf(w4.w, xv3.x, acc[r].x); acc[r].y = fmaf(w4.w, xv3.y, acc[r].y);
                acc[r].z = fmaf(w4.w, xv3.z, acc[r].z); acc[r].w = fmaf(w4.w, xv3.w, acc[r].w);
                wsum[r] += (w4.x + w4.y) + (w4.z + w4.w);
            }
        }
        __syncthreads();
    }

#pragma unroll
    for (int r = 0; r < 4; ++r) {
        int i = i0 + g * 4 + r;
        float dn = wsum[r] + 1e-8f;
        float inv = 1.0f / dn;
        float4 rf = ((const float4*)(ref + (size_t)i * DIM))[s];
        float4 o;
        o.x = acc[r].x * inv - rf.x;
        o.y = acc[r].y * inv - rf.y;
        o.z = acc[r].z * inv - rf.z;
        o.w = acc[r].w * inv - rf.w;
        ((float4*)(out + ((size_t)b * NREF + i) * DIM))[s] = o;
    }
}

extern "C" void kernel_launch(void* const* d_in, const int* in_sizes, int n_in,
                              void* d_out, int out_size, void* d_ws, size_t ws_size,
                              hipStream_t stream) {
    const float* X   = (const float*)d_in[0];
    const float* ref = (const float*)d_in[1];
    float* out = (float*)d_out;

    char* ws = (char*)d_ws;
    size_t off = 0;
    float* C   = (float*)(ws + off); off += (size_t)BATCH * NREF * NPTS * sizeof(float);
    float* u   = (float*)(ws + off); off += (size_t)BATCH * NREF * sizeof(float);
    float* vb0 = (float*)(ws + off); off += (size_t)BATCH * NPTS * sizeof(float);
    size_t off_nodbuf = off;
    size_t off_dbuf   = off + (size_t)BATCH * NPTS * sizeof(float);
    const size_t tail = 2048;                 // r2 (1 KB) + meta (1 KB)
    bool dbuf = (ws_size >= off_dbuf + tail); // fall back to aliased v if ws is tight:
    float* vb1 = dbuf ? (float*)(ws + off_nodbuf) + 0 : vb0;
    if (dbuf) vb1 = (float*)(ws + off_nodbuf); // vb1 lives right after vb0
    size_t toff = dbuf ? off_dbuf : off_nodbuf;
    float* r2 = (float*)(ws + toff);
    unsigned int* meta    = (unsigned int*)(ws + toff + 1024);
    unsigned int* flags   = meta;             // [ITERS]: bit0 consec-changed, bit1 period2-changed
    unsigned int* cnt     = meta + ITERS;     // [ITERS]: block-done counters
    unsigned int* stop    = meta + 2 * ITERS;
    unsigned int* final_p = meta + 2 * ITERS + 1;

    const float log_wx = (float)log(1.0 / (double)NREF + 1e-8);
    const float log_wy = (float)log(1.0 / (double)NPTS + 1e-8);

    hipMemsetAsync(vb1, 0, (size_t)BATCH * NPTS * sizeof(float), stream);  // v^(-1) = 0
    hipMemsetAsync(meta, 0, 1024, stream);                                 // flags/cnt/stop reset

    r2_kernel<<<1, 256, 0, stream>>>(ref, r2);
    c_kernel<<<BATCH * 32, 256, 0, stream>>>(X, ref, r2, C);

    for (int t = 0; t < ITERS; ++t) {
        float* vprev = (t & 1) ? vb0 : vb1;   // t=0 reads vb1 (zeros)
        float* vcur  = (t & 1) ? vb1 : vb0;
        u_kernel<<<BATCH * NREF / 4, 256, 0, stream>>>(C, vprev, u, log_wx, stop);
        v_kernel<<<BATCH * 32, 256, 0, stream>>>(C, u, vprev, vcur, log_wy,
                                                 flags + t, cnt + t, stop, final_p, t);
    }

    out_kernel<<<BATCH * 8, 256, 0, stream>>>(C, X, ref, u, vb0, vb1, final_p, out);
}

// Round 2
// 4404.307 us; speedup vs baseline: 3.3443x; 3.3443x over previous
//
#include <hip/hip_runtime.h>
#include <math.h>

#define BATCH 64
#define NREF  256
#define NPTS  2048
#define DIM   128
#define ITERS 100
#define INV_EPS 1000.0f
#define RCHUNK 16
#define NCHUNK (NREF / RCHUNK)   // 16 chunks of 16 rows

// Scaled (logit) domain throughout: u' = u/eps, v' = v/eps, C' = C/eps.

__device__ __forceinline__ void lse_step(float t, float& m, float& s) {
    float nm = fmaxf(m, t);
    float e  = __expf(m + t - 2.0f * nm);      // exp(-|m-t|); 0 when m==-inf
    float s1 = fmaf(s, e, 1.0f);               // t is new max
    float s2 = s + e;                          // t <= m
    s = (t > m) ? s1 : s2;
    m = nm;
}
__device__ __forceinline__ void lse_combine(float& m, float& s, float mo, float so) {
    float nm = fmaxf(m, mo);
    s = s * __expf(m - nm) + so * __expf(mo - nm);
    m = nm;
}

// ---------- ref row norms ----------
__global__ __launch_bounds__(256) void r2_kernel(const float* __restrict__ ref,
                                                 float* __restrict__ r2) {
    int i = threadIdx.x;
    const float4* r4 = (const float4*)(ref + (size_t)i * DIM);
    float acc = 0.f;
#pragma unroll
    for (int k = 0; k < DIM / 4; ++k) {
        float4 a = r4[k];
        acc += a.x * a.x + a.y * a.y + a.z * a.z + a.w * a.w;
    }
    r2[i] = acc;
}

// ---------- C'[b][i][j] = sqrt(max(r2_i + x2_bj - 2*dot(ref_i, X_bj), 0)) * INV_EPS ----------
__global__ __launch_bounds__(256) void c_kernel(const float* __restrict__ X,
                                                const float* __restrict__ ref,
                                                const float* __restrict__ r2,
                                                float* __restrict__ C) {
    int b  = blockIdx.x >> 5;
    int it = (blockIdx.x >> 3) & 3;
    int jc = blockIdx.x & 7;
    int j  = jc * 256 + threadIdx.x;
    int i0 = it * 64;
    const float* xrow = X + ((size_t)b * NPTS + j) * DIM;

    float acc[64];
#pragma unroll
    for (int i = 0; i < 64; ++i) acc[i] = 0.f;
    float x2 = 0.f;

    for (int k0 = 0; k0 < DIM; k0 += 16) {
        float xv[16];
        const float4* xp = (const float4*)(xrow + k0);
#pragma unroll
        for (int q = 0; q < 4; ++q) {
            float4 t = xp[q];
            xv[q * 4 + 0] = t.x; xv[q * 4 + 1] = t.y;
            xv[q * 4 + 2] = t.z; xv[q * 4 + 3] = t.w;
        }
#pragma unroll
        for (int k = 0; k < 16; ++k) x2 = fmaf(xv[k], xv[k], x2);

        const float* rbase = ref + (size_t)i0 * DIM + k0;   // block-uniform -> s_load
#pragma unroll
        for (int i = 0; i < 64; ++i) {
            const float* rr = rbase + (size_t)i * DIM;
#pragma unroll
            for (int k = 0; k < 16; ++k) acc[i] = fmaf(rr[k], xv[k], acc[i]);
        }
    }

    float* cbase = C + ((size_t)b * NREF + i0) * NPTS + j;
#pragma unroll
    for (int i = 0; i < 64; ++i) {
        float sq = r2[i0 + i] + x2 - 2.f * acc[i];
        cbase[(size_t)i * NPTS] = sqrtf(fmaxf(sq, 0.f)) * INV_EPS;
    }
}

// ============================================================================
// FUSED PATH: read C once per iteration.
// uv_kernel: block = (b, 16-row chunk), 256 threads, full 2048 columns.
//   Thread owns cols {4t..4t+3} and {1024+4t..1024+4t+3}; C-tile lives in
//   float4 a[16] / bb[16] registers (128 VGPRs).
//   Phase A: exact row-LSE (block reduce)  -> u_new for the 16 rows.
//   Phase B: per-owned-column partial LSE over the 16 rows, using
//     u - C = (t + u_loc) - v_j  with t = v - C already in regs; the
//     per-column constant -v_j just shifts the partial max.
// vmerge_kernel: combine the 16 chunk partials per (b,j) -> v_new.
// ============================================================================
__global__ __launch_bounds__(256, 2) void uv_kernel(const float* __restrict__ C,
                                                    const float* __restrict__ v,
                                                    float* __restrict__ u,
                                                    float* __restrict__ Pm,
                                                    float* __restrict__ Ps,
                                                    float log_wx) {
    __shared__ float smx[4][RCHUNK];
    __shared__ float sms[4][RCHUNK];
    int b     = blockIdx.x >> 4;
    int chunk = blockIdx.x & 15;
    int t     = threadIdx.x;
    int lane  = t & 63;
    int w     = t >> 6;

    const float* Cb = C + (size_t)(b * NREF + chunk * RCHUNK) * NPTS;
    const float* vb = v + (size_t)b * NPTS;

    float4 va = *(const float4*)(vb + 4 * t);
    float4 vc = *(const float4*)(vb + 1024 + 4 * t);

    // issue all 32 tile loads up front (MLP; lands directly in the reg tile)
    float4 a[RCHUNK], bb[RCHUNK];
#pragma unroll
    for (int i = 0; i < RCHUNK; ++i) {
        const float* row = Cb + (size_t)i * NPTS;
        a[i]  = *(const float4*)(row + 4 * t);
        bb[i] = *(const float4*)(row + 1024 + 4 * t);
    }

    // t = v - C (in place), local row max over 8 owned values
    float mloc[RCHUNK];
#pragma unroll
    for (int i = 0; i < RCHUNK; ++i) {
        a[i].x  = va.x - a[i].x;  a[i].y  = va.y - a[i].y;
        a[i].z  = va.z - a[i].z;  a[i].w  = va.w - a[i].w;
        bb[i].x = vc.x - bb[i].x; bb[i].y = vc.y - bb[i].y;
        bb[i].z = vc.z - bb[i].z; bb[i].w = vc.w - bb[i].w;
        float m0 = fmaxf(fmaxf(a[i].x, a[i].y), fmaxf(a[i].z, a[i].w));
        float m1 = fmaxf(fmaxf(bb[i].x, bb[i].y), fmaxf(bb[i].z, bb[i].w));
        mloc[i] = fmaxf(m0, m1);
    }
    // block reduce max per row
#pragma unroll
    for (int i = 0; i < RCHUNK; ++i)
#pragma unroll
        for (int off = 1; off < 64; off <<= 1)
            mloc[i] = fmaxf(mloc[i], __shfl_xor(mloc[i], off));
    if (lane == 0) {
#pragma unroll
        for (int i = 0; i < RCHUNK; ++i) smx[w][i] = mloc[i];
    }
    __syncthreads();
    float mf[RCHUNK];
#pragma unroll
    for (int i = 0; i < RCHUNK; ++i)
        mf[i] = fmaxf(fmaxf(smx[0][i], smx[1][i]), fmaxf(smx[2][i], smx[3][i]));

    // exact-shifted row sums
    float sloc[RCHUNK];
#pragma unroll
    for (int i = 0; i < RCHUNK; ++i) {
        float s = __expf(a[i].x - mf[i]) + __expf(a[i].y - mf[i])
                + __expf(a[i].z - mf[i]) + __expf(a[i].w - mf[i])
                + __expf(bb[i].x - mf[i]) + __expf(bb[i].y - mf[i])
                + __expf(bb[i].z - mf[i]) + __expf(bb[i].w - mf[i]);
        sloc[i] = s;
    }
#pragma unroll
    for (int i = 0; i < RCHUNK; ++i)
#pragma unroll
        for (int off = 1; off < 64; off <<= 1)
            sloc[i] += __shfl_xor(sloc[i], off);
    if (lane == 0) {
#pragma unroll
        for (int i = 0; i < RCHUNK; ++i) sms[w][i] = sloc[i];
    }
    __syncthreads();

    float uloc[RCHUNK];
#pragma unroll
    for (int i = 0; i < RCHUNK; ++i) {
        float s = (sms[0][i] + sms[1][i]) + (sms[2][i] + sms[3][i]);
        uloc[i] = log_wx - (mf[i] + __logf(s));
    }
    // write u (16 predicated single-lane stores; needed only for out_kernel)
    int ub = b * NREF + chunk * RCHUNK;
#pragma unroll
    for (int i = 0; i < RCHUNK; ++i)
        if (t == i) u[ub + i] = uloc[i];

    // Phase B: per-column partial LSE over the 16 rows.
    // arg = u - C = (t + uloc) - v_j ; -v_j shifts the partial max only.
#define COLLSE(ARR, Q, MD, SD)                                              \
    {                                                                       \
        float m_ = -INFINITY;                                               \
        _Pragma("unroll")                                                   \
        for (int i_ = 0; i_ < RCHUNK; ++i_)                                 \
            m_ = fmaxf(m_, ARR[i_].Q + uloc[i_]);                           \
        float s_ = 0.f;                                                     \
        _Pragma("unroll")                                                   \
        for (int i_ = 0; i_ < RCHUNK; ++i_)                                 \
            s_ += __expf(ARR[i_].Q + uloc[i_] - m_);                        \
        MD = m_; SD = s_;                                                   \
    }

    float4 pm0, ps0, pm1, ps1;
    COLLSE(a,  x, pm0.x, ps0.x) COLLSE(a,  y, pm0.y, ps0.y)
    COLLSE(a,  z, pm0.z, ps0.z) COLLSE(a,  w, pm0.w, ps0.w)
    COLLSE(bb, x, pm1.x, ps1.x) COLLSE(bb, y, pm1.y, ps1.y)
    COLLSE(bb, z, pm1.z, ps1.z) COLLSE(bb, w, pm1.w, ps1.w)
#undef COLLSE
    pm0.x -= va.x; pm0.y -= va.y; pm0.z -= va.z; pm0.w -= va.w;
    pm1.x -= vc.x; pm1.y -= vc.y; pm1.z -= vc.z; pm1.w -= vc.w;

    size_t pbase = (size_t)(b * NCHUNK + chunk) * NPTS;
    *(float4*)(Pm + pbase + 4 * t) = pm0;
    *(float4*)(Ps + pbase + 4 * t) = ps0;
    *(float4*)(Pm + pbase + 1024 + 4 * t) = pm1;
    *(float4*)(Ps + pbase + 1024 + 4 * t) = ps1;
}

__global__ __launch_bounds__(256) void vmerge_kernel(const float* __restrict__ Pm,
                                                     const float* __restrict__ Ps,
                                                     float* __restrict__ v,
                                                     float log_wy) {
    int b = blockIdx.x >> 3;
    int j = ((blockIdx.x & 7) << 8) + threadIdx.x;
    size_t base = (size_t)b * NCHUNK * NPTS + j;
    float m = Pm[base];
    float s = Ps[base];
#pragma unroll
    for (int c = 1; c < NCHUNK; ++c) {
        float mo = Pm[base + (size_t)c * NPTS];
        float so = Ps[base + (size_t)c * NPTS];
        lse_combine(m, s, mo, so);
    }
    v[(size_t)b * NPTS + j] = log_wy - (m + __logf(s));
}

// ============================================================================
// LEGACY PATH (round-0, used only if workspace can't hold the partial planes)
// ============================================================================
__global__ __launch_bounds__(256) void u_kernel(const float* __restrict__ C,
                                                const float* __restrict__ v,
                                                float* __restrict__ u,
                                                float log_wx) {
    int row  = blockIdx.x * 4 + (threadIdx.x >> 6);   // b*256 + i
    int lane = threadIdx.x & 63;
    int b    = row >> 8;
    const float4* crow = (const float4*)(C + (size_t)row * NPTS);
    const float4* vrow = (const float4*)(v + (size_t)b * NPTS);

    float4 t[8];
    float m = -INFINITY;
#pragma unroll
    for (int c = 0; c < 8; ++c) {
        float4 cv = crow[c * 64 + lane];
        float4 vv = vrow[c * 64 + lane];
        float4 tt;
        tt.x = vv.x - cv.x; tt.y = vv.y - cv.y;
        tt.z = vv.z - cv.z; tt.w = vv.w - cv.w;
        t[c] = tt;
        m = fmaxf(m, fmaxf(fmaxf(tt.x, tt.y), fmaxf(tt.z, tt.w)));
    }
#pragma unroll
    for (int off = 1; off < 64; off <<= 1) m = fmaxf(m, __shfl_xor(m, off));

    float s0 = 0.f, s1 = 0.f, s2 = 0.f, s3 = 0.f;
#pragma unroll
    for (int c = 0; c < 8; ++c) {
        s0 += __expf(t[c].x - m);
        s1 += __expf(t[c].y - m);
        s2 += __expf(t[c].z - m);
        s3 += __expf(t[c].w - m);
    }
    float s = (s0 + s1) + (s2 + s3);
#pragma unroll
    for (int off = 1; off < 64; off <<= 1) s += __shfl_xor(s, off);

    if (lane == 0) u[row] = log_wx - (m + __logf(s));
}

__global__ __launch_bounds__(256) void v_kernel(const float* __restrict__ C,
                                                const float* __restrict__ u,
                                                float* __restrict__ vout,
                                                float log_wy) {
    __shared__ float sm[4][64];
    __shared__ float ss[4][64];
    int b  = blockIdx.x >> 5;
    int jc = blockIdx.x & 31;
    int jj = threadIdx.x & 63;
    int g  = threadIdx.x >> 6;
    int j  = jc * 64 + jj;
    const float* cg = C + ((size_t)b * NREF + (size_t)g * 64) * NPTS + j;
    const float* ub = u + (size_t)b * NREF + g * 64;

    float m0 = -INFINITY, s0 = 0.f, m1 = -INFINITY, s1 = 0.f;
#pragma unroll 8
    for (int i = 0; i < 64; i += 2) {
        float c0 = cg[(size_t)(i + 0) * NPTS];
        float c1 = cg[(size_t)(i + 1) * NPTS];
        lse_step(ub[i + 0] - c0, m0, s0);
        lse_step(ub[i + 1] - c1, m1, s1);
    }
    lse_combine(m0, s0, m1, s1);
    sm[g][jj] = m0; ss[g][jj] = s0;
    __syncthreads();
    if (g == 0) {
        float m = m0, s = s0;
#pragma unroll
        for (int q = 1; q < 4; ++q) lse_combine(m, s, sm[q][jj], ss[q][jj]);
        vout[(size_t)b * NPTS + j] = log_wy - (m + __logf(s));
    }
}

// ---------- epilogue: GEMM-style register tiling ----------
__global__ __launch_bounds__(256) void out_kernel(const float* __restrict__ C,
                                                  const float* __restrict__ X,
                                                  const float* __restrict__ ref,
                                                  const float* __restrict__ u,
                                                  const float* __restrict__ v,
                                                  float* __restrict__ out) {
    __shared__ float wt[32 * 32];       // [row_local][jj]  4 KB
    __shared__ float xt[32 * DIM];      // [jj][d]         16 KB
    int b  = blockIdx.x >> 3;
    int it = blockIdx.x & 7;
    int i0 = it * 32;
    int t  = threadIdx.x;
    int s  = t & 31;                    // d-slot (float4 at d = 4s)
    int g  = t >> 5;                    // rows i0 + g*4 .. +3

    const float* Cb = C + ((size_t)b * NREF + i0) * NPTS;
    const float* vb = v + (size_t)b * NPTS;
    const float* ub = u + (size_t)b * NREF + i0;

    float4 acc[4];
    float wsum[4];
#pragma unroll
    for (int r = 0; r < 4; ++r) { acc[r] = make_float4(0.f, 0.f, 0.f, 0.f); wsum[r] = 0.f; }

    for (int j0 = 0; j0 < NPTS; j0 += 32) {
#pragma unroll
        for (int k = 0; k < 4; ++k) {
            int widx = t + 256 * k;
            int r    = widx >> 5;
            int jj   = widx & 31;
            wt[widx] = __expf(ub[r] + vb[j0 + jj] - Cb[(size_t)r * NPTS + j0 + jj]);
        }
        const float4* Xb4 = (const float4*)(X + ((size_t)b * NPTS + j0) * DIM);
#pragma unroll
        for (int k = 0; k < 4; ++k) {
            int idx = t + 256 * k;
            ((float4*)xt)[idx] = Xb4[idx];
        }
        __syncthreads();

        const float4* xt4 = (const float4*)xt;
#pragma unroll 2
        for (int jj = 0; jj < 32; jj += 4) {
            float4 xv0 = xt4[(jj + 0) * 32 + s];
            float4 xv1 = xt4[(jj + 1) * 32 + s];
            float4 xv2 = xt4[(jj + 2) * 32 + s];
            float4 xv3 = xt4[(jj + 3) * 32 + s];
#pragma unroll
            for (int r = 0; r < 4; ++r) {
                float4 w4 = *(const float4*)&wt[(g * 4 + r) * 32 + jj];
                acc[r].x = fmaf(w4.x, xv0.x, acc[r].x); acc[r].y = fmaf(w4.x, xv0.y, acc[r].y);
                acc[r].z = fmaf(w4.x, xv0.z, acc[r].z); acc[r].w = fmaf(w4.x, xv0.w, acc[r].w);
                acc[r].x = fmaf(w4.y, xv1.x, acc[r].x); acc[r].y = fmaf(w4.y, xv1.y, acc[r].y);
                acc[r].z = fmaf(w4.y, xv1.z, acc[r].z); acc[r].w = fmaf(w4.y, xv1.w, acc[r].w);
                acc[r].x = fmaf(w4.z, xv2.x, acc[r].x); acc[r].y = fmaf(w4.z, xv2.y, acc[r].y);
                acc[r].z = fmaf(w4.z, xv2.z, acc[r].z); acc[r].w = fmaf(w4.z, xv2.w, acc[r].w);
                acc[r].x = fmaf(w4.w, xv3.x, acc[r].x); acc[r].y = fmaf(w4.w, xv3.y, acc[r].y);
                acc[r].z = fmaf(w4.w, xv3.z, acc[r].z); acc[r].w = fmaf(w4.w, xv3.w, acc[r].w);
                wsum[r] += (w4.x + w4.y) + (w4.z + w4.w);
            }
        }
        __syncthreads();
    }

#pragma unroll
    for (int r = 0; r < 4; ++r) {
        int i = i0 + g * 4 + r;
        float dn = wsum[r] + 1e-8f;
        float inv = 1.0f / dn;
        float4 rf = ((const float4*)(ref + (size_t)i * DIM))[s];
        float4 o;
        o.x = acc[r].x * inv - rf.x;
        o.y = acc[r].y * inv - rf.y;
        o.z = acc[r].z * inv - rf.z;
        o.w = acc[r].w * inv - rf.w;
        ((float4*)(out + ((size_t)b * NREF + i) * DIM))[s] = o;
    }
}

extern "C" void kernel_launch(void* const* d_in, const int* in_sizes, int n_in,
                              void* d_out, int out_size, void* d_ws, size_t ws_size,
                              hipStream_t stream) {
    const float* X   = (const float*)d_in[0];
    const float* ref = (const float*)d_in[1];
    float* out = (float*)d_out;

    char* ws = (char*)d_ws;
    size_t o = 0;
    float* C  = (float*)(ws + o); o += (size_t)BATCH * NREF * NPTS * sizeof(float);
    float* u  = (float*)(ws + o); o += (size_t)BATCH * NREF * sizeof(float);
    float* v  = (float*)(ws + o); o += (size_t)BATCH * NPTS * sizeof(float);
    float* r2 = (float*)(ws + o); o += 1024;
    size_t szP = (size_t)BATCH * NCHUNK * NPTS * sizeof(float);   // 8 MiB each
    float* Pm = (float*)(ws + o); o += szP;
    float* Ps = (float*)(ws + o); o += szP;
    bool fused = (ws_size >= o);

    const float log_wx = (float)log(1.0 / (double)NREF + 1e-8);
    const float log_wy = (float)log(1.0 / (double)NPTS + 1e-8);

    hipMemsetAsync(v, 0, (size_t)BATCH * NPTS * sizeof(float), stream);

    r2_kernel<<<1, 256, 0, stream>>>(ref, r2);
    c_kernel<<<BATCH * 32, 256, 0, stream>>>(X, ref, r2, C);

    if (fused) {
        for (int t = 0; t < ITERS; ++t) {
            uv_kernel<<<BATCH * NCHUNK, 256, 0, stream>>>(C, v, u, Pm, Ps, log_wx);
            vmerge_kernel<<<BATCH * NPTS / 256, 256, 0, stream>>>(Pm, Ps, v, log_wy);
        }
    } else {
        for (int t = 0; t < ITERS; ++t) {
            u_kernel<<<BATCH * NREF / 4, 256, 0, stream>>>(C, v, u, log_wx);
            v_kernel<<<BATCH * 32, 256, 0, stream>>>(C, u, v, log_wy);
        }
    }

    out_kernel<<<BATCH * 8, 256, 0, stream>>>(C, X, ref, u, v, out);
}

// Round 3
// 4344.235 us; speedup vs baseline: 3.3905x; 1.0138x over previous
//
#include <hip/hip_runtime.h>
#include <math.h>

#define BATCH 64
#define NREF  256
#define NPTS  2048
#define DIM   128
#define ITERS 100
#define INV_EPS 1000.0f
#define RCHUNK 16
#define NCHUNK (NREF / RCHUNK)   // 16 chunks of 16 rows

// Scaled (logit) domain throughout: u' = u/eps, v' = v/eps, C' = C/eps.

// ---------- ref row norms ----------
__global__ __launch_bounds__(256) void r2_kernel(const float* __restrict__ ref,
                                                 float* __restrict__ r2) {
    int i = threadIdx.x;
    const float4* r4 = (const float4*)(ref + (size_t)i * DIM);
    float acc = 0.f;
#pragma unroll
    for (int k = 0; k < DIM / 4; ++k) {
        float4 a = r4[k];
        acc += a.x * a.x + a.y * a.y + a.z * a.z + a.w * a.w;
    }
    r2[i] = acc;
}

// ---------- X row norms: block = 16 rows x 16 lanes (coalesced 512B/row) ----------
__global__ __launch_bounds__(256) void x2_kernel(const float* __restrict__ X,
                                                 float* __restrict__ x2) {
    int r = threadIdx.x >> 4;            // local row 0..15
    int c = threadIdx.x & 15;            // k-slot
    int j = blockIdx.x * 16 + r;         // flat row in [0, BATCH*NPTS)
    const float4* xp = (const float4*)(X + (size_t)j * DIM + c * 8);
    float4 a = xp[0], b = xp[1];
    float acc = a.x * a.x + a.y * a.y + a.z * a.z + a.w * a.w
              + b.x * b.x + b.y * b.y + b.z * b.z + b.w * b.w;
#pragma unroll
    for (int off = 1; off < 16; off <<= 1) acc += __shfl_xor(acc, off);
    if (c == 0) x2[j] = acc;
}

// ---------- C' via GEMM tiling: block computes 128i x 128j of one batch ----------
// LDS: rs[k][i], xs[k][j] (8x128 each). Thread (ti,tj) covers i in
// {ti*4..+3, 64+ti*4..+3} x j in {tj*4..+3, 64+tj*4..+3} -> 8x8 accs.
__global__ __launch_bounds__(256) void cgemm_kernel(const float* __restrict__ X,
                                                    const float* __restrict__ ref,
                                                    const float* __restrict__ r2,
                                                    const float* __restrict__ x2,
                                                    float* __restrict__ C) {
    __shared__ float rs[8 * 128];
    __shared__ float xs[8 * 128];
    int b  = blockIdx.x >> 5;
    int it = (blockIdx.x >> 4) & 1;
    int jt = blockIdx.x & 15;
    int i0 = it * 128, j0 = jt * 128;
    int t  = threadIdx.x;
    int ti = t >> 4, tj = t & 15;

    int sr = t >> 1;                     // staging row 0..127
    int sh = (t & 1) * 4;                // k-offset 0 or 4
    const float* refp = ref + (size_t)(i0 + sr) * DIM + sh;
    const float* xp   = X + ((size_t)b * NPTS + j0 + sr) * DIM + sh;

    float4 acc[2][2][4];
#pragma unroll
    for (int p = 0; p < 2; ++p)
#pragma unroll
        for (int q = 0; q < 2; ++q)
#pragma unroll
            for (int ii = 0; ii < 4; ++ii)
                acc[p][q][ii] = make_float4(0.f, 0.f, 0.f, 0.f);

    for (int k0 = 0; k0 < DIM; k0 += 8) {
        float4 rv = *(const float4*)(refp + k0);
        float4 xv = *(const float4*)(xp + k0);
        __syncthreads();                 // previous compute done before overwrite
        rs[(sh + 0) * 128 + sr] = rv.x; rs[(sh + 1) * 128 + sr] = rv.y;
        rs[(sh + 2) * 128 + sr] = rv.z; rs[(sh + 3) * 128 + sr] = rv.w;
        xs[(sh + 0) * 128 + sr] = xv.x; xs[(sh + 1) * 128 + sr] = xv.y;
        xs[(sh + 2) * 128 + sr] = xv.z; xs[(sh + 3) * 128 + sr] = xv.w;
        __syncthreads();

        const float4* rs4 = (const float4*)rs;
        const float4* xs4 = (const float4*)xs;
#pragma unroll
        for (int k = 0; k < 8; ++k) {
            float4 a0 = rs4[k * 32 + ti];
            float4 a1 = rs4[k * 32 + 16 + ti];
            float4 b0 = xs4[k * 32 + tj];
            float4 b1 = xs4[k * 32 + 16 + tj];
#define FMA4(ACC, S, BV)                                                     \
            ACC.x = fmaf(S, BV.x, ACC.x); ACC.y = fmaf(S, BV.y, ACC.y);      \
            ACC.z = fmaf(S, BV.z, ACC.z); ACC.w = fmaf(S, BV.w, ACC.w);
#define ROW(P, S, II)                                                        \
            FMA4(acc[P][0][II], S, b0) FMA4(acc[P][1][II], S, b1)
            ROW(0, a0.x, 0) ROW(0, a0.y, 1) ROW(0, a0.z, 2) ROW(0, a0.w, 3)
            ROW(1, a1.x, 0) ROW(1, a1.y, 1) ROW(1, a1.z, 2) ROW(1, a1.w, 3)
#undef ROW
#undef FMA4
        }
    }

    float4 x2v[2];
    x2v[0] = *(const float4*)(x2 + (size_t)b * NPTS + j0 + tj * 4);
    x2v[1] = *(const float4*)(x2 + (size_t)b * NPTS + j0 + 64 + tj * 4);
#pragma unroll
    for (int p = 0; p < 2; ++p)
#pragma unroll
        for (int ii = 0; ii < 4; ++ii) {
            int i = i0 + p * 64 + ti * 4 + ii;
            float rr = r2[i];
            float* crow = C + ((size_t)b * NREF + i) * NPTS + j0;
#pragma unroll
            for (int q = 0; q < 2; ++q) {
                float4 av = acc[p][q][ii];
                float4 o;
                o.x = sqrtf(fmaxf(rr + x2v[q].x - 2.f * av.x, 0.f)) * INV_EPS;
                o.y = sqrtf(fmaxf(rr + x2v[q].y - 2.f * av.y, 0.f)) * INV_EPS;
                o.z = sqrtf(fmaxf(rr + x2v[q].z - 2.f * av.z, 0.f)) * INV_EPS;
                o.w = sqrtf(fmaxf(rr + x2v[q].w - 2.f * av.w, 0.f)) * INV_EPS;
                *(float4*)(crow + q * 64 + tj * 4) = o;
            }
        }
}

// ---------- fused u+column-partial: 512 threads, thread owns ONE float4 col slot ----------
// Tile a[16] = 64 VGPR; launch_bounds(512,4) caps at 128 VGPR -> 2 blocks/CU (16 waves).
// Partials stored pre-merged: l = m + log(s) (halves partial traffic vs (m,s)).
__global__ __launch_bounds__(512, 4) void uv_kernel(const float* __restrict__ C,
                                                    const float* __restrict__ v,
                                                    float* __restrict__ u,
                                                    float* __restrict__ Pl,
                                                    float log_wx) {
    __shared__ float smx[RCHUNK][8];
    __shared__ float sms[RCHUNK][8];
    int b     = blockIdx.x >> 4;
    int chunk = blockIdx.x & 15;
    int t     = threadIdx.x;
    int lane  = t & 63;
    int w     = t >> 6;

    const float* Cb = C + (size_t)(b * NREF + chunk * RCHUNK) * NPTS;
    float4 vj = *(const float4*)(v + (size_t)b * NPTS + 4 * t);

    float4 a[RCHUNK];
#pragma unroll
    for (int i = 0; i < RCHUNK; ++i)
        a[i] = *(const float4*)(Cb + (size_t)i * NPTS + 4 * t);

    float m[RCHUNK], su[RCHUNK];
#pragma unroll
    for (int i = 0; i < RCHUNK; ++i) {
        a[i].x = vj.x - a[i].x; a[i].y = vj.y - a[i].y;
        a[i].z = vj.z - a[i].z; a[i].w = vj.w - a[i].w;
        m[i] = fmaxf(fmaxf(a[i].x, a[i].y), fmaxf(a[i].z, a[i].w));
    }
#pragma unroll
    for (int i = 0; i < RCHUNK; ++i)
#pragma unroll
        for (int off = 1; off < 64; off <<= 1)
            m[i] = fmaxf(m[i], __shfl_xor(m[i], off));
    if (lane == 0) {
#pragma unroll
        for (int i = 0; i < RCHUNK; ++i) smx[i][w] = m[i];
    }
    __syncthreads();
#pragma unroll
    for (int i = 0; i < RCHUNK; ++i) {
        float mm = smx[i][0];
#pragma unroll
        for (int q = 1; q < 8; ++q) mm = fmaxf(mm, smx[i][q]);
        m[i] = mm;
    }
    // exact-shifted row sums
#pragma unroll
    for (int i = 0; i < RCHUNK; ++i)
        su[i] = __expf(a[i].x - m[i]) + __expf(a[i].y - m[i])
              + __expf(a[i].z - m[i]) + __expf(a[i].w - m[i]);
#pragma unroll
    for (int i = 0; i < RCHUNK; ++i)
#pragma unroll
        for (int off = 1; off < 64; off <<= 1)
            su[i] += __shfl_xor(su[i], off);
    if (lane == 0) {
#pragma unroll
        for (int i = 0; i < RCHUNK; ++i) sms[i][w] = su[i];
    }
    __syncthreads();
#pragma unroll
    for (int i = 0; i < RCHUNK; ++i) {
        float s = ((sms[i][0] + sms[i][1]) + (sms[i][2] + sms[i][3]))
                + ((sms[i][4] + sms[i][5]) + (sms[i][6] + sms[i][7]));
        su[i] = log_wx - (m[i] + __logf(s));    // su := u_new for row i
    }
    int ub = b * NREF + chunk * RCHUNK;
#pragma unroll
    for (int i = 0; i < RCHUNK; ++i)
        if (t == i) u[ub + i] = su[i];

    // column partial LSE over the 16 rows; arg = u - C = a + su - v_j
    float4 pl;
#define COLL(Q)                                                              \
    {                                                                        \
        float mq = a[0].Q + su[0];                                           \
        _Pragma("unroll")                                                    \
        for (int i_ = 1; i_ < RCHUNK; ++i_)                                  \
            mq = fmaxf(mq, a[i_].Q + su[i_]);                                \
        float sq_ = 0.f;                                                     \
        _Pragma("unroll")                                                    \
        for (int i_ = 0; i_ < RCHUNK; ++i_)                                  \
            sq_ += __expf(a[i_].Q + su[i_] - mq);                            \
        pl.Q = (mq - vj.Q) + __logf(sq_);                                    \
    }
    COLL(x) COLL(y) COLL(z) COLL(w)
#undef COLL
    *(float4*)(Pl + (size_t)(b * NCHUNK + chunk) * NPTS + 4 * t) = pl;
}

// ---------- merge 16 chunk logits per column -> v ----------
__global__ __launch_bounds__(256) void vmerge_kernel(const float* __restrict__ Pl,
                                                     float* __restrict__ v,
                                                     float log_wy) {
    int b = blockIdx.x >> 3;
    int j = ((blockIdx.x & 7) << 8) + threadIdx.x;
    const float* p = Pl + (size_t)b * NCHUNK * NPTS + j;
    float l[NCHUNK];
#pragma unroll
    for (int c = 0; c < NCHUNK; ++c) l[c] = p[(size_t)c * NPTS];
    float m = l[0];
#pragma unroll
    for (int c = 1; c < NCHUNK; ++c) m = fmaxf(m, l[c]);
    float s = 0.f;
#pragma unroll
    for (int c = 0; c < NCHUNK; ++c) s += __expf(l[c] - m);
    v[(size_t)b * NPTS + j] = log_wy - (m + __logf(s));
}

// ---------- epilogue: GEMM-style register tiling ----------
__global__ __launch_bounds__(256) void out_kernel(const float* __restrict__ C,
                                                  const float* __restrict__ X,
                                                  const float* __restrict__ ref,
                                                  const float* __restrict__ u,
                                                  const float* __restrict__ v,
                                                  float* __restrict__ out) {
    __shared__ float wt[32 * 32];       // [row_local][jj]  4 KB
    __shared__ float xt[32 * DIM];      // [jj][d]         16 KB
    int b  = blockIdx.x >> 3;
    int it = blockIdx.x & 7;
    int i0 = it * 32;
    int t  = threadIdx.x;
    int s  = t & 31;                    // d-slot (float4 at d = 4s)
    int g  = t >> 5;                    // rows i0 + g*4 .. +3

    const float* Cb = C + ((size_t)b * NREF + i0) * NPTS;
    const float* vb = v + (size_t)b * NPTS;
    const float* ub = u + (size_t)b * NREF + i0;

    float4 acc[4];
    float wsum[4];
#pragma unroll
    for (int r = 0; r < 4; ++r) { acc[r] = make_float4(0.f, 0.f, 0.f, 0.f); wsum[r] = 0.f; }

    for (int j0 = 0; j0 < NPTS; j0 += 32) {
#pragma unroll
        for (int k = 0; k < 4; ++k) {
            int widx = t + 256 * k;
            int r    = widx >> 5;
            int jj   = widx & 31;
            wt[widx] = __expf(ub[r] + vb[j0 + jj] - Cb[(size_t)r * NPTS + j0 + jj]);
        }
        const float4* Xb4 = (const float4*)(X + ((size_t)b * NPTS + j0) * DIM);
#pragma unroll
        for (int k = 0; k < 4; ++k) {
            int idx = t + 256 * k;
            ((float4*)xt)[idx] = Xb4[idx];
        }
        __syncthreads();

        const float4* xt4 = (const float4*)xt;
#pragma unroll 2
        for (int jj = 0; jj < 32; jj += 4) {
            float4 xv0 = xt4[(jj + 0) * 32 + s];
            float4 xv1 = xt4[(jj + 1) * 32 + s];
            float4 xv2 = xt4[(jj + 2) * 32 + s];
            float4 xv3 = xt4[(jj + 3) * 32 + s];
#pragma unroll
            for (int r = 0; r < 4; ++r) {
                float4 w4 = *(const float4*)&wt[(g * 4 + r) * 32 + jj];
                acc[r].x = fmaf(w4.x, xv0.x, acc[r].x); acc[r].y = fmaf(w4.x, xv0.y, acc[r].y);
                acc[r].z = fmaf(w4.x, xv0.z, acc[r].z); acc[r].w = fmaf(w4.x, xv0.w, acc[r].w);
                acc[r].x = fmaf(w4.y, xv1.x, acc[r].x); acc[r].y = fmaf(w4.y, xv1.y, acc[r].y);
                acc[r].z = fmaf(w4.y, xv1.z, acc[r].z); acc[r].w = fmaf(w4.y, xv1.w, acc[r].w);
                acc[r].x = fmaf(w4.z, xv2.x, acc[r].x); acc[r].y = fmaf(w4.z, xv2.y, acc[r].y);
                acc[r].z = fmaf(w4.z, xv2.z, acc[r].z); acc[r].w = fmaf(w4.z, xv2.w, acc[r].w);
                acc[r].x = fmaf(w4.w, xv3.x, acc[r].x); acc[r].y = fmaf(w4.w, xv3.y, acc[r].y);
                acc[r].z = fmaf(w4.w, xv3.z, acc[r].z); acc[r].w = fmaf(w4.w, xv3.w, acc[r].w);
                wsum[r] += (w4.x + w4.y) + (w4.z + w4.w);
            }
        }
        __syncthreads();
    }

#pragma unroll
    for (int r = 0; r < 4; ++r) {
        int i = i0 + g * 4 + r;
        float dn = wsum[r] + 1e-8f;
        float inv = 1.0f / dn;
        float4 rf = ((const float4*)(ref + (size_t)i * DIM))[s];
        float4 o;
        o.x = acc[r].x * inv - rf.x;
        o.y = acc[r].y * inv - rf.y;
        o.z = acc[r].z * inv - rf.z;
        o.w = acc[r].w * inv - rf.w;
        ((float4*)(out + ((size_t)b * NREF + i) * DIM))[s] = o;
    }
}

extern "C" void kernel_launch(void* const* d_in, const int* in_sizes, int n_in,
                              void* d_out, int out_size, void* d_ws, size_t ws_size,
                              hipStream_t stream) {
    const float* X   = (const float*)d_in[0];
    const float* ref = (const float*)d_in[1];
    float* out = (float*)d_out;

    char* ws = (char*)d_ws;
    size_t o = 0;
    float* C  = (float*)(ws + o); o += (size_t)BATCH * NREF * NPTS * sizeof(float);
    float* u  = (float*)(ws + o); o += (size_t)BATCH * NREF * sizeof(float);
    float* v  = (float*)(ws + o); o += (size_t)BATCH * NPTS * sizeof(float);
    float* r2 = (float*)(ws + o); o += 4096;
    float* x2 = (float*)(ws + o); o += (size_t)BATCH * NPTS * sizeof(float);
    float* Pl = (float*)(ws + o); o += (size_t)BATCH * NCHUNK * NPTS * sizeof(float);

    const float log_wx = (float)log(1.0 / (double)NREF + 1e-8);
    const float log_wy = (float)log(1.0 / (double)NPTS + 1e-8);

    hipMemsetAsync(v, 0, (size_t)BATCH * NPTS * sizeof(float), stream);

    x2_kernel<<<BATCH * NPTS / 16, 256, 0, stream>>>(X, x2);
    r2_kernel<<<1, 256, 0, stream>>>(ref, r2);
    cgemm_kernel<<<BATCH * 32, 256, 0, stream>>>(X, ref, r2, x2, C);

    for (int t = 0; t < ITERS; ++t) {
        uv_kernel<<<BATCH * NCHUNK, 512, 0, stream>>>(C, v, u, Pl, log_wx);
        vmerge_kernel<<<BATCH * NPTS / 256, 256, 0, stream>>>(Pl, v, log_wy);
    }

    out_kernel<<<BATCH * 8, 256, 0, stream>>>(C, X, ref, u, v, out);
}